// Round 9
// baseline (641.193 us; speedup 1.0000x reference)
//
#include <hip/hip_runtime.h>
#include <cstddef>

// B=64, T=512, H=256. Float inputs fp32 (runtime-detected, bf16 fallback).
// Output fp32: [out_s (B*T), out_e (B*T)].
// ws layout (bytes):
//   0        W5q   640*256 u32 bf16-pair B-frags, uint4-grouped:
//                  idx = ((p>>2)*256+col)*4+(p&3); p: 0..127 W1f, 128..255
//                  W1fq+W1fm, 256..383 W1afq+afm, 384..511 Wr, 512..639 Wh
//   1310720  Urp   128*256 u32  (bf16 pairs along i)
//   1441792  Uhp   128*256 u32
//   1572864  qw1   64*256 f32
//   1638400  qs    64 f32
//   1638656  qe    64 f32
//   1638912  att   64*512 f32
//   1901056  xrh   64*512*256 u32
// 3 launches: k_prep, k_main (64-row tiles, 512 blocks), k_scan (softmax+out fused).

static __device__ __forceinline__ float b2f(unsigned short u) {
  return __uint_as_float(((unsigned)u) << 16);
}
static __device__ __forceinline__ float blo(unsigned w) { return __uint_as_float(w << 16); }
static __device__ __forceinline__ float bhi(unsigned w) { return __uint_as_float(w & 0xffff0000u); }
static __device__ __forceinline__ unsigned short f2b(float f) {
  unsigned u = __float_as_uint(f);
  u += 0x7fffu + ((u >> 16) & 1u);  // RNE
  return (unsigned short)(u >> 16);
}
static __device__ __forceinline__ float ldf(const void* b, size_t i, int md) {
  return md ? ((const float*)b)[i] : b2f(((const unsigned short*)b)[i]);
}
static __device__ __forceinline__ unsigned short ldb(const void* b, size_t i, int md) {
  return md ? f2b(((const float*)b)[i]) : ((const unsigned short*)b)[i];
}
static __device__ __forceinline__ unsigned pack2(float a, float b) {
  return (unsigned)f2b(a) | ((unsigned)f2b(b) << 16);
}
// inline dtype detection: wave-local, no barrier, same result in every wave.
static __device__ __forceinline__ int detect_mode(const void* fact) {
  const unsigned short* u = (const unsigned short*)fact;
  int lane = threadIdx.x & 63;
  float v = 0.f;
#pragma unroll
  for (int k = 0; k < 4; ++k) {
    float x = fabsf(b2f(u[2 * (lane + 64 * k)]));
    x = (x == x) ? x : 1e30f;
    v = fmaxf(v, x);
  }
  for (int o = 32; o > 0; o >>= 1) v = fmaxf(v, __shfl_xor(v, o));
  return v > 1e4f ? 1 : 0;
}
static __device__ __forceinline__ float4 ld4(const void* p, size_t i, int md) {
  if (md) return *(const float4*)((const float*)p + i);
  const unsigned short* u = (const unsigned short*)p + i;
  uint2 w = *(const uint2*)u;
  float4 r;
  r.x = blo(w.x); r.y = bhi(w.x); r.z = blo(w.y); r.w = bhi(w.y);
  return r;
}

typedef short bfrag __attribute__((ext_vector_type(8)));
typedef float f32x4 __attribute__((ext_vector_type(4)));

template <int CTRL>
static __device__ __forceinline__ float dpp_add(float x) {
  int v = __builtin_amdgcn_update_dpp(0, __float_as_int(x), CTRL, 0xF, 0xF, true);
  return x + __int_as_float(v);
}
static __device__ __forceinline__ float red16(float x) {
  x = dpp_add<0xB1>(x);
  x = dpp_add<0x4E>(x);
  x = dpp_add<0x141>(x);
  x = dpp_add<0x140>(x);
  return x;
}
static __device__ __forceinline__ void sync_lds() {
  __builtin_amdgcn_fence(__ATOMIC_RELEASE, "workgroup", "local");
  __builtin_amdgcn_s_barrier();
  __builtin_amdgcn_fence(__ATOMIC_ACQUIRE, "workgroup", "local");
}
static __device__ __forceinline__ float fast_tanh(float x) {
  float xc = fminf(fmaxf(x, -15.f), 15.f);
  return 1.f - 2.f * __builtin_amdgcn_rcpf(__expf(2.f * xc) + 1.f);
}

// ---------------- merged prep: packed weights (blocks 0..127) + q vectors (128..191) ----------------
__global__ void k_prep(const void* __restrict__ fact,
                       const void* __restrict__ W1,
                       const void* __restrict__ Wr,
                       const void* __restrict__ Wh,
                       const void* __restrict__ Ur,
                       const void* __restrict__ Uh,
                       const void* __restrict__ q,
                       const void* __restrict__ b1,
                       const void* __restrict__ Ws,
                       const void* __restrict__ bs,
                       const void* __restrict__ We,
                       const void* __restrict__ be,
                       unsigned* __restrict__ W5q,
                       unsigned* __restrict__ Urp,
                       unsigned* __restrict__ Uhp,
                       float* __restrict__ qw1,
                       float* __restrict__ qs,
                       float* __restrict__ qe) {
  __shared__ float qsh[256];
  __shared__ float reds[4], rede[4];
  int md = detect_mode(fact);
  int tid = threadIdx.x;
  if (blockIdx.x < 128) {
    int idx = blockIdx.x * 256 + tid;  // 0..32767
    int i = idx >> 8, j = idx & 255;
    Urp[idx] = (unsigned)ldb(Ur, (size_t)(2 * i) * 256 + j, md) |
               ((unsigned)ldb(Ur, (size_t)(2 * i + 1) * 256 + j, md) << 16);
    Uhp[idx] = (unsigned)ldb(Uh, (size_t)(2 * i) * 256 + j, md) |
               ((unsigned)ldb(Uh, (size_t)(2 * i + 1) * 256 + j, md) << 16);
    float v0, v1;
    int p;
    p = i;
    v0 = ldf(W1, (size_t)(2 * i) * 256 + j, md);
    v1 = ldf(W1, (size_t)(2 * i + 1) * 256 + j, md);
    W5q[(((p >> 2) * 256 + j) << 2) + (p & 3)] = pack2(v0, v1);
    p = 128 + i;
    v0 = ldf(W1, (size_t)(768 + 2 * i) * 256 + j, md) + ldf(W1, (size_t)(1024 + 2 * i) * 256 + j, md);
    v1 = ldf(W1, (size_t)(769 + 2 * i) * 256 + j, md) + ldf(W1, (size_t)(1025 + 2 * i) * 256 + j, md);
    W5q[(((p >> 2) * 256 + j) << 2) + (p & 3)] = pack2(v0, v1);
    p = 256 + i;
    v0 = ldf(W1, (size_t)(1280 + 2 * i) * 256 + j, md) + ldf(W1, (size_t)(1536 + 2 * i) * 256 + j, md);
    v1 = ldf(W1, (size_t)(1281 + 2 * i) * 256 + j, md) + ldf(W1, (size_t)(1537 + 2 * i) * 256 + j, md);
    W5q[(((p >> 2) * 256 + j) << 2) + (p & 3)] = pack2(v0, v1);
    p = 384 + i;
    v0 = ldf(Wr, (size_t)(2 * i) * 256 + j, md);
    v1 = ldf(Wr, (size_t)(2 * i + 1) * 256 + j, md);
    W5q[(((p >> 2) * 256 + j) << 2) + (p & 3)] = pack2(v0, v1);
    p = 512 + i;
    v0 = ldf(Wh, (size_t)(2 * i) * 256 + j, md);
    v1 = ldf(Wh, (size_t)(2 * i + 1) * 256 + j, md);
    W5q[(((p >> 2) * 256 + j) << 2) + (p & 3)] = pack2(v0, v1);
  } else {
    int b = blockIdx.x - 128;  // 0..63
    float qv = ldf(q, (size_t)b * 256 + tid, md);
    qsh[tid] = qv;
    __syncthreads();
    float acc = ldf(b1, tid, md);
#pragma unroll 8
    for (int i = 0; i < 256; ++i) {
      float w = ldf(W1, (size_t)(256 + i) * 256 + tid, md) + ldf(W1, (size_t)(512 + i) * 256 + tid, md);
      acc = fmaf(qsh[i], w, acc);
    }
    qw1[b * 256 + tid] = acc;
    float ps = qv * ldf(Ws, tid, md);
    float pe = qv * ldf(We, tid, md);
    for (int o = 32; o > 0; o >>= 1) { ps += __shfl_down(ps, o); pe += __shfl_down(pe, o); }
    int wave = tid >> 6, lane = tid & 63;
    if (lane == 0) { reds[wave] = ps; rede[wave] = pe; }
    __syncthreads();
    if (tid == 0) {
      qs[b] = ldf(bs, 0, md) + reds[0] + reds[1] + reds[2] + reds[3];
      qe[b] = ldf(be, 0, md) + rede[0] + rede[1] + rede[2] + rede[3];
    }
  }
}

// ---------------- main GEMM via MFMA: att pre-softmax + xr/xh ----------------
// 64 t-rows per block (512 blocks, 512 threads, 8 waves): waves 0-3 own rows
// 0-31, waves 4-7 rows 32-63; each wave 64 cols x 32 rows (same per-wave regs
// as the 32-row version). W5q L2/L3 traffic halves (512 x 655 KB = 335 MB).
// xrh stores are nontemporal so the 33 MB write stream doesn't evict W5q
// from L2. A-tile 97 KB LDS (CDNA4: 160 KB/CU), 1 block/CU, 2 rounds.
__launch_bounds__(512, 1)
__global__ void k_main(const void* __restrict__ fact,
                       const void* __restrict__ q,
                       const unsigned* __restrict__ W5q,
                       const float* __restrict__ qw1,
                       const void* __restrict__ W2,
                       const void* __restrict__ b2v,
                       const void* __restrict__ br,
                       const void* __restrict__ bh,
                       float* __restrict__ att,
                       unsigned* __restrict__ xrh) {
  __shared__ __align__(16) unsigned short A[64 * 776];  // 97 KB
  __shared__ float wsc[64][4];
  int md = detect_mode(fact);
  int blk = blockIdx.x;
  int b = blk >> 3, t0 = (blk & 7) * 64;
  int tid = threadIdx.x;  // 0..511
  {
    int c4 = (tid & 63) * 4;  // column group, fixed per thread
    int rg = tid >> 6;        // 0..7
    float4 q4 = ld4(q, (size_t)b * 256 + c4, md);
#pragma unroll
    for (int s = 0; s < 8; ++s) {
      int r = rg * 8 + s;  // 0..63
      float4 f4 = ld4(fact, ((size_t)(b * 512 + t0 + r)) * 256 + c4, md);
      char* base = (char*)A + (size_t)r * 1552 + (size_t)c4 * 2;
      uint2 w0 = {pack2(f4.x, f4.y), pack2(f4.z, f4.w)};
      uint2 w1 = {pack2(f4.x * q4.x, f4.y * q4.y), pack2(f4.z * q4.z, f4.w * q4.w)};
      uint2 w2 = {pack2(fabsf(f4.x - q4.x), fabsf(f4.y - q4.y)),
                  pack2(fabsf(f4.z - q4.z), fabsf(f4.w - q4.w))};
      *(uint2*)(base) = w0;
      *(uint2*)(base + 512) = w1;
      *(uint2*)(base + 1024) = w2;
    }
  }
  __syncthreads();
  int wv = tid >> 6, lane = tid & 63;
  int n16 = lane & 15, quad = lane >> 4;
  int rbase = (wv >> 2) * 32;        // 0 or 32
  int colb = (wv & 3) * 64 + n16;    // col-wave ownership
  const uint4* W4 = (const uint4*)W5q;
  f32x4 z = {0.f, 0.f, 0.f, 0.f};
  f32x4 u[2][4], ar[2][4], ah[2][4];
#pragma unroll
  for (int rt = 0; rt < 2; ++rt)
#pragma unroll
    for (int tile = 0; tile < 4; ++tile) { u[rt][tile] = z; ar[rt][tile] = z; ah[rt][tile] = z; }
#pragma unroll
  for (int kc = 0; kc < 8; ++kc) {
    uint4 av0 = *(const uint4*)((const char*)A + (rbase + n16) * 1552 + kc * 64 + quad * 16);
    uint4 av1 = *(const uint4*)((const char*)A + (rbase + 16 + n16) * 1552 + kc * 64 + quad * 16);
    bfrag af0 = __builtin_bit_cast(bfrag, av0);
    bfrag af1 = __builtin_bit_cast(bfrag, av1);
    int pg = kc * 4 + quad;
#pragma unroll
    for (int tile = 0; tile < 4; ++tile) {
      int col = colb + tile * 16;
      uint4 bu = W4[(size_t)pg * 256 + col];
      uint4 bw = W4[(size_t)(96 + pg) * 256 + col];
      uint4 bv = W4[(size_t)(128 + pg) * 256 + col];
      bfrag bfu = __builtin_bit_cast(bfrag, bu);
      bfrag bfw = __builtin_bit_cast(bfrag, bw);
      bfrag bfv = __builtin_bit_cast(bfrag, bv);
      u[0][tile] = __builtin_amdgcn_mfma_f32_16x16x32_bf16(af0, bfu, u[0][tile], 0, 0, 0);
      u[1][tile] = __builtin_amdgcn_mfma_f32_16x16x32_bf16(af1, bfu, u[1][tile], 0, 0, 0);
      ar[0][tile] = __builtin_amdgcn_mfma_f32_16x16x32_bf16(af0, bfw, ar[0][tile], 0, 0, 0);
      ar[1][tile] = __builtin_amdgcn_mfma_f32_16x16x32_bf16(af1, bfw, ar[1][tile], 0, 0, 0);
      ah[0][tile] = __builtin_amdgcn_mfma_f32_16x16x32_bf16(af0, bfv, ah[0][tile], 0, 0, 0);
      ah[1][tile] = __builtin_amdgcn_mfma_f32_16x16x32_bf16(af1, bfv, ah[1][tile], 0, 0, 0);
    }
  }
#pragma unroll
  for (int kc = 8; kc < 24; ++kc) {
    uint4 av0 = *(const uint4*)((const char*)A + (rbase + n16) * 1552 + kc * 64 + quad * 16);
    uint4 av1 = *(const uint4*)((const char*)A + (rbase + 16 + n16) * 1552 + kc * 64 + quad * 16);
    bfrag af0 = __builtin_bit_cast(bfrag, av0);
    bfrag af1 = __builtin_bit_cast(bfrag, av1);
    int pg = kc * 4 + quad;
#pragma unroll
    for (int tile = 0; tile < 4; ++tile) {
      int col = colb + tile * 16;
      uint4 bu = W4[(size_t)pg * 256 + col];
      bfrag bfu = __builtin_bit_cast(bfrag, bu);
      u[0][tile] = __builtin_amdgcn_mfma_f32_16x16x32_bf16(af0, bfu, u[0][tile], 0, 0, 0);
      u[1][tile] = __builtin_amdgcn_mfma_f32_16x16x32_bf16(af1, bfu, u[1][tile], 0, 0, 0);
    }
  }
  float qwv[4], w2v[4], brv[4], bhv[4];
#pragma unroll
  for (int tile = 0; tile < 4; ++tile) {
    int col = colb + tile * 16;
    qwv[tile] = qw1[b * 256 + col];
    w2v[tile] = ldf(W2, col, md);
    brv[tile] = ldf(br, col, md);
    bhv[tile] = ldf(bh, col, md);
  }
  float ps[2][4];
#pragma unroll
  for (int rt = 0; rt < 2; ++rt)
#pragma unroll
    for (int reg = 0; reg < 4; ++reg) {
      float p = 0.f;
#pragma unroll
      for (int tile = 0; tile < 4; ++tile) {
        float hid = fast_tanh(u[rt][tile][reg] + qwv[tile]);
        p = fmaf(hid, w2v[tile], p);
      }
      ps[rt][reg] = red16(p);
    }
  if (n16 == 0) {
#pragma unroll
    for (int rt = 0; rt < 2; ++rt)
#pragma unroll
      for (int reg = 0; reg < 4; ++reg)
        wsc[rbase + rt * 16 + quad * 4 + reg][wv & 3] = ps[rt][reg];
  }
  __syncthreads();
  if (tid < 64) {
    att[b * 512 + t0 + tid] =
        wsc[tid][0] + wsc[tid][1] + wsc[tid][2] + wsc[tid][3] + ldf(b2v, 0, md);
  }
#pragma unroll
  for (int rt = 0; rt < 2; ++rt)
#pragma unroll
    for (int tile = 0; tile < 4; ++tile) {
      int col = colb + tile * 16;
#pragma unroll
      for (int reg = 0; reg < 4; ++reg) {
        int t = t0 + rbase + rt * 16 + quad * 4 + reg;
        unsigned v = (unsigned)f2b(ar[rt][tile][reg] + brv[tile]) |
                     ((unsigned)f2b(ah[rt][tile][reg] + bhv[tile]) << 16);
        __builtin_nontemporal_store(v, &xrh[((size_t)(b * 512 + t)) * 256 + col]);
      }
    }
}

// ---------------- MFMA GRU scan: 4 batches/block, 16 blocks, 8 waves ----------------
// Round-3 structure + fused out-projection (deferred atomics) + fused softmax.
// gbuf/sacc/eacc padded to stride 520 (bank offset 8 per row).
__launch_bounds__(512, 2)
__global__ void k_scan(const unsigned* __restrict__ Urp,
                       const unsigned* __restrict__ Uhp,
                       const unsigned* __restrict__ xrh,
                       const float* __restrict__ att,
                       const int* __restrict__ input_len,
                       const void* __restrict__ Ws,
                       const void* __restrict__ We,
                       const float* __restrict__ qs,
                       const float* __restrict__ qe,
                       const void* __restrict__ fact,
                       float* __restrict__ out) {
  __shared__ __align__(16) unsigned short hB[4 * 272];
  __shared__ __align__(16) unsigned short rhB[4 * 272];
  __shared__ float sacc[4][520];
  __shared__ float eacc[4][520];
  __shared__ float gbuf[4][520];
  __shared__ float redx[8];
  int md = detect_mode(fact);
  int b0 = blockIdx.x * 4;
  int tid = threadIdx.x;  // 0..511
  int wv = tid >> 6, lane = tid & 63;
  int n16 = lane & 15, quad = lane >> 4;
  int col0 = wv * 32 + n16;
  int col1 = col0 + 16;
  uint4 br4[2][8], bh4[2][8];
#pragma unroll
  for (int tile = 0; tile < 2; ++tile) {
    int col = wv * 32 + tile * 16 + n16;
#pragma unroll
    for (int kc = 0; kc < 8; ++kc) {
      int p = kc * 16 + quad * 4;
      uint4 rv = {Urp[(size_t)p * 256 + col], Urp[(size_t)(p + 1) * 256 + col],
                  Urp[(size_t)(p + 2) * 256 + col], Urp[(size_t)(p + 3) * 256 + col]};
      uint4 hv = {Uhp[(size_t)p * 256 + col], Uhp[(size_t)(p + 1) * 256 + col],
                  Uhp[(size_t)(p + 2) * 256 + col], Uhp[(size_t)(p + 3) * 256 + col]};
      br4[tile][kc] = rv;
      bh4[tile][kc] = hv;
    }
  }
  for (int i = tid; i < 4 * 272; i += 512) { hB[i] = 0; rhB[i] = 0; }
  for (int i = tid; i < 2080; i += 512) { ((float*)sacc)[i] = 0.f; ((float*)eacc)[i] = 0.f; }
  // ---- fused softmax: att[b0+bb][:] -> gbuf[bb][:] ----
#pragma unroll
  for (int bb = 0; bb < 4; ++bb) {
    float v = att[(size_t)(b0 + bb) * 512 + tid];
    float m = v;
    for (int o = 32; o > 0; o >>= 1) m = fmaxf(m, __shfl_xor(m, o));
    if (lane == 0) redx[wv] = m;
    __syncthreads();
    m = redx[0];
#pragma unroll
    for (int w = 1; w < 8; ++w) m = fmaxf(m, redx[w]);
    float e = __expf(v - m);
    float s = e;
    for (int o = 32; o > 0; o >>= 1) s += __shfl_xor(s, o);
    __syncthreads();
    if (lane == 0) redx[wv] = s;
    __syncthreads();
    s = redx[0] + redx[1] + redx[2] + redx[3] + redx[4] + redx[5] + redx[6] + redx[7];
    gbuf[bb][tid] = e / s;
  }
  int mylen = input_len[b0 + quad];
  float ws0 = ldf(Ws, 256 + col0, md), ws1 = ldf(Ws, 256 + col1, md);
  float we0 = ldf(We, 256 + col0, md), we1 = ldf(We, 256 + col1, md);
  float hm0 = 0.f, hm1 = 0.f;  // this lane's h for (batch=quad, col0/col1)
  float pend_s = 0.f, pend_e = 0.f;
  int pend_T = 0;
  const char* hbase = (const char*)hB + (n16 >> 2) * 544 + quad * 16;
  const char* rhbase = (const char*)rhB + (n16 >> 2) * 544 + quad * 16;
  const unsigned* xrow = xrh + (size_t)(b0 + quad) * 512 * 256;

  unsigned xa[16], xbb[16];
  float4 ga0, ga1, gb0, gb1;
  __syncthreads();  // gbuf complete before prefetch reads it
  auto prefetch = [&](int tb, unsigned (&xr)[16], float4& g0, float4& g1) {
    const unsigned* xp = xrow + (size_t)tb * 8 * 256;
#pragma unroll
    for (int s = 0; s < 8; ++s) {
      xr[2 * s] = xp[s * 256 + col0];
      xr[2 * s + 1] = xp[s * 256 + col1];
    }
    g0 = *(const float4*)&gbuf[quad][tb * 8];
    g1 = *(const float4*)&gbuf[quad][tb * 8 + 4];
  };
  prefetch(0, xa, ga0, ga1);
  const f32x4 z4 = {0.f, 0.f, 0.f, 0.f};

  auto step = [&](int T, unsigned XC0, unsigned XC1, float GT) {
    // ---- phase A: rpre = h @ Ur (2 tiles, depth-2 chains) ----
    f32x4 accA[2][4];
#pragma unroll
    for (int tl = 0; tl < 2; ++tl)
#pragma unroll
      for (int j = 0; j < 4; ++j) accA[tl][j] = z4;
#pragma unroll
    for (int kc = 0; kc < 8; ++kc) {
      uint4 av = *(const uint4*)(hbase + kc * 64);
      bfrag af = __builtin_bit_cast(bfrag, av);
      int j = kc & 3;
      accA[0][j] = __builtin_amdgcn_mfma_f32_16x16x32_bf16(af, __builtin_bit_cast(bfrag, br4[0][kc]), accA[0][j], 0, 0, 0);
      accA[1][j] = __builtin_amdgcn_mfma_f32_16x16x32_bf16(af, __builtin_bit_cast(bfrag, br4[1][kc]), accA[1][j], 0, 0, 0);
    }
    // deferred out-projection reduce of PREVIOUS step — overlaps MFMA drain
    {
      float rs = red16(pend_s);
      float re_ = red16(pend_e);
      if (n16 == 0) {
        atomicAdd(&sacc[quad][pend_T], rs);
        atomicAdd(&eacc[quad][pend_T], re_);
      }
    }
    {
      float v0 = (accA[0][0][0] + accA[0][1][0]) + (accA[0][2][0] + accA[0][3][0]);
      float v1 = (accA[1][0][0] + accA[1][1][0]) + (accA[1][2][0] + accA[1][3][0]);
      float e0 = __expf(-(v0 + blo(XC0)));
      float e1 = __expf(-(v1 + blo(XC1)));
      float r0 = __builtin_amdgcn_rcpf(1.f + e0);
      float r1 = __builtin_amdgcn_rcpf(1.f + e1);
      rhB[quad * 272 + col0] = f2b(r0 * hm0);
      rhB[quad * 272 + col1] = f2b(r1 * hm1);
    }
    sync_lds();
    // ---- phase B: hpre = (r*h) @ Uh ----
    f32x4 accB[2][4];
#pragma unroll
    for (int tl = 0; tl < 2; ++tl)
#pragma unroll
      for (int j = 0; j < 4; ++j) accB[tl][j] = z4;
#pragma unroll
    for (int kc = 0; kc < 8; ++kc) {
      uint4 av = *(const uint4*)(rhbase + kc * 64);
      bfrag af = __builtin_bit_cast(bfrag, av);
      int j = kc & 3;
      accB[0][j] = __builtin_amdgcn_mfma_f32_16x16x32_bf16(af, __builtin_bit_cast(bfrag, bh4[0][kc]), accB[0][j], 0, 0, 0);
      accB[1][j] = __builtin_amdgcn_mfma_f32_16x16x32_bf16(af, __builtin_bit_cast(bfrag, bh4[1][kc]), accB[1][j], 0, 0, 0);
    }
    {
      float w0 = (accB[0][0][0] + accB[0][1][0]) + (accB[0][2][0] + accB[0][3][0]);
      float w1 = (accB[1][0][0] + accB[1][1][0]) + (accB[1][2][0] + accB[1][3][0]);
      float c0 = fminf(fmaxf(w0 + bhi(XC0), -15.f), 15.f);
      float c1 = fminf(fmaxf(w1 + bhi(XC1), -15.f), 15.f);
      float hc0 = 1.f - 2.f * __builtin_amdgcn_rcpf(__expf(2.f * c0) + 1.f);
      float hc1 = 1.f - 2.f * __builtin_amdgcn_rcpf(__expf(2.f * c1) + 1.f);
      bool valid = T < mylen;
      float hn0 = hm0 + GT * (hc0 - hm0);
      float hn1 = hm1 + GT * (hc1 - hm1);
      hm0 = valid ? hn0 : hm0;
      hm1 = valid ? hn1 : hm1;
      hB[quad * 272 + col0] = f2b(hm0);
      hB[quad * 272 + col1] = f2b(hm1);
      // stash out-projection partials; reduced during next phase A
      pend_s = valid ? fmaf(hm0, ws0, hm1 * ws1) : 0.f;
      pend_e = valid ? fmaf(hm0, we0, hm1 * we1) : 0.f;
      pend_T = T;
    }
    sync_lds();
  };

  for (int tb2 = 0; tb2 < 32; ++tb2) {
    prefetch(2 * tb2 + 1, xbb, gb0, gb1);
#pragma unroll
    for (int tt = 0; tt < 8; ++tt)
      step(tb2 * 16 + tt, xa[2 * tt], xa[2 * tt + 1], tt < 4 ? ga0[tt] : ga1[tt - 4]);
    prefetch(tb2 < 31 ? 2 * tb2 + 2 : 63, xa, ga0, ga1);
#pragma unroll
    for (int tt = 0; tt < 8; ++tt)
      step(tb2 * 16 + 8 + tt, xbb[2 * tt], xbb[2 * tt + 1], tt < 4 ? gb0[tt] : gb1[tt - 4]);
  }
  // final pending flush (T = 511)
  {
    float rs = red16(pend_s);
    float re_ = red16(pend_e);
    if (n16 == 0) {
      atomicAdd(&sacc[quad][pend_T], rs);
      atomicAdd(&eacc[quad][pend_T], re_);
    }
  }
  sync_lds();
  for (int i = tid; i < 2048; i += 512) {
    int b = i >> 9, t = i & 511;
    int row = (b0 + b) * 512 + t;
    out[row] = tanhf(qs[b0 + b] + sacc[b][t]);
    out[32768 + row] = tanhf(qe[b0 + b] + eacc[b][t]);
  }
}

extern "C" void kernel_launch(void* const* d_in, const int* in_sizes, int n_in,
                              void* d_out, int out_size, void* d_ws, size_t ws_size,
                              hipStream_t stream) {
  const void* q    = d_in[0];
  const void* fact = d_in[1];
  const int* ilen  = (const int*)d_in[2];
  const void* W1   = d_in[3];
  const void* b1   = d_in[4];
  const void* W2   = d_in[5];
  const void* b2v  = d_in[6];
  const void* Wr   = d_in[7];
  const void* Ur   = d_in[8];
  const void* br   = d_in[9];
  const void* Wh   = d_in[10];
  const void* Uh   = d_in[11];
  const void* bh   = d_in[12];
  const void* Ws   = d_in[13];
  const void* bs   = d_in[14];
  const void* We   = d_in[15];
  const void* be   = d_in[16];

  char* w = (char*)d_ws;
  unsigned* W5q = (unsigned*)(w);
  unsigned* Urp = (unsigned*)(w + 1310720);
  unsigned* Uhp = (unsigned*)(w + 1441792);
  float*    qw1 = (float*)(w + 1572864);
  float*    qs  = (float*)(w + 1638400);
  float*    qe  = (float*)(w + 1638656);
  float*    att = (float*)(w + 1638912);
  unsigned* xrh = (unsigned*)(w + 1901056);
  float* out = (float*)d_out;

  k_prep<<<dim3(192), dim3(256), 0, stream>>>(fact, W1, Wr, Wh, Ur, Uh, q, b1, Ws, bs, We, be,
                                              W5q, Urp, Uhp, qw1, qs, qe);
  k_main<<<dim3(512), dim3(512), 0, stream>>>(fact, q, W5q, qw1, W2, b2v, br, bh, att, xrh);
  k_scan<<<dim3(16), dim3(512), 0, stream>>>(Urp, Uhp, xrh, att, ilen, Ws, We, qs, qe, fact, out);
}

// Round 11
// 634.917 us; speedup vs baseline: 1.0099x; 1.0099x over previous
//
#include <hip/hip_runtime.h>
#include <cstddef>

// B=64, T=512, H=256. Float inputs fp32 (runtime-detected, bf16 fallback).
// Output fp32: [out_s (B*T), out_e (B*T)].
// ws layout (bytes):
//   0        W5q   640*256 u32 bf16-pair B-frags, uint4-grouped:
//                  idx = ((p>>2)*256+col)*4+(p&3); p: 0..127 W1f, 128..255
//                  W1fq+W1fm, 256..383 W1afq+afm, 384..511 Wr, 512..639 Wh
//   1310720  Urp   128*256 u32  (bf16 pairs along i)
//   1441792  Uhp   128*256 u32
//   1572864  qw1   64*256 f32
//   1638400  qs    64 f32
//   1638656  qe    64 f32
//   1638912  att   64*512 f32
//   1901056  xrh   64*512*256 u32
// 3 launches: k_prep, k_main (64-row tiles, 512 blocks), k_scan (softmax+out fused).

static __device__ __forceinline__ float b2f(unsigned short u) {
  return __uint_as_float(((unsigned)u) << 16);
}
static __device__ __forceinline__ float blo(unsigned w) { return __uint_as_float(w << 16); }
static __device__ __forceinline__ float bhi(unsigned w) { return __uint_as_float(w & 0xffff0000u); }
static __device__ __forceinline__ unsigned short f2b(float f) {
  unsigned u = __float_as_uint(f);
  u += 0x7fffu + ((u >> 16) & 1u);  // RNE
  return (unsigned short)(u >> 16);
}
static __device__ __forceinline__ float ldf(const void* b, size_t i, int md) {
  return md ? ((const float*)b)[i] : b2f(((const unsigned short*)b)[i]);
}
static __device__ __forceinline__ unsigned short ldb(const void* b, size_t i, int md) {
  return md ? f2b(((const float*)b)[i]) : ((const unsigned short*)b)[i];
}
static __device__ __forceinline__ unsigned pack2(float a, float b) {
  return (unsigned)f2b(a) | ((unsigned)f2b(b) << 16);
}
// inline dtype detection: wave-local, no barrier, same result in every wave.
static __device__ __forceinline__ int detect_mode(const void* fact) {
  const unsigned short* u = (const unsigned short*)fact;
  int lane = threadIdx.x & 63;
  float v = 0.f;
#pragma unroll
  for (int k = 0; k < 4; ++k) {
    float x = fabsf(b2f(u[2 * (lane + 64 * k)]));
    x = (x == x) ? x : 1e30f;
    v = fmaxf(v, x);
  }
  for (int o = 32; o > 0; o >>= 1) v = fmaxf(v, __shfl_xor(v, o));
  return v > 1e4f ? 1 : 0;
}
static __device__ __forceinline__ float4 ld4(const void* p, size_t i, int md) {
  if (md) return *(const float4*)((const float*)p + i);
  const unsigned short* u = (const unsigned short*)p + i;
  uint2 w = *(const uint2*)u;
  float4 r;
  r.x = blo(w.x); r.y = bhi(w.x); r.z = blo(w.y); r.w = bhi(w.y);
  return r;
}

typedef short bfrag __attribute__((ext_vector_type(8)));
typedef float f32x4 __attribute__((ext_vector_type(4)));

template <int CTRL>
static __device__ __forceinline__ float dpp_add(float x) {
  int v = __builtin_amdgcn_update_dpp(0, __float_as_int(x), CTRL, 0xF, 0xF, true);
  return x + __int_as_float(v);
}
static __device__ __forceinline__ float red16(float x) {
  x = dpp_add<0xB1>(x);
  x = dpp_add<0x4E>(x);
  x = dpp_add<0x141>(x);
  x = dpp_add<0x140>(x);
  return x;
}
// LDS-only barrier: drain lgkmcnt (LDS ops) but leave global prefetch loads
// (vmcnt) in flight across the barrier — T4 "never drain vmcnt in the loop".
// The h/rh exchange only needs LDS ordering; LDS is CU-local, no cache.
static __device__ __forceinline__ void sync_lds() {
  asm volatile("s_waitcnt lgkmcnt(0)" ::: "memory");
  __builtin_amdgcn_s_barrier();
}
static __device__ __forceinline__ float fast_tanh(float x) {
  float xc = fminf(fmaxf(x, -15.f), 15.f);
  return 1.f - 2.f * __builtin_amdgcn_rcpf(__expf(2.f * xc) + 1.f);
}

// ---------------- merged prep: packed weights (blocks 0..127) + q vectors (128..191) ----------------
__global__ void k_prep(const void* __restrict__ fact,
                       const void* __restrict__ W1,
                       const void* __restrict__ Wr,
                       const void* __restrict__ Wh,
                       const void* __restrict__ Ur,
                       const void* __restrict__ Uh,
                       const void* __restrict__ q,
                       const void* __restrict__ b1,
                       const void* __restrict__ Ws,
                       const void* __restrict__ bs,
                       const void* __restrict__ We,
                       const void* __restrict__ be,
                       unsigned* __restrict__ W5q,
                       unsigned* __restrict__ Urp,
                       unsigned* __restrict__ Uhp,
                       float* __restrict__ qw1,
                       float* __restrict__ qs,
                       float* __restrict__ qe) {
  __shared__ float qsh[256];
  __shared__ float reds[4], rede[4];
  int md = detect_mode(fact);
  int tid = threadIdx.x;
  if (blockIdx.x < 128) {
    int idx = blockIdx.x * 256 + tid;  // 0..32767
    int i = idx >> 8, j = idx & 255;
    Urp[idx] = (unsigned)ldb(Ur, (size_t)(2 * i) * 256 + j, md) |
               ((unsigned)ldb(Ur, (size_t)(2 * i + 1) * 256 + j, md) << 16);
    Uhp[idx] = (unsigned)ldb(Uh, (size_t)(2 * i) * 256 + j, md) |
               ((unsigned)ldb(Uh, (size_t)(2 * i + 1) * 256 + j, md) << 16);
    float v0, v1;
    int p;
    p = i;
    v0 = ldf(W1, (size_t)(2 * i) * 256 + j, md);
    v1 = ldf(W1, (size_t)(2 * i + 1) * 256 + j, md);
    W5q[(((p >> 2) * 256 + j) << 2) + (p & 3)] = pack2(v0, v1);
    p = 128 + i;
    v0 = ldf(W1, (size_t)(768 + 2 * i) * 256 + j, md) + ldf(W1, (size_t)(1024 + 2 * i) * 256 + j, md);
    v1 = ldf(W1, (size_t)(769 + 2 * i) * 256 + j, md) + ldf(W1, (size_t)(1025 + 2 * i) * 256 + j, md);
    W5q[(((p >> 2) * 256 + j) << 2) + (p & 3)] = pack2(v0, v1);
    p = 256 + i;
    v0 = ldf(W1, (size_t)(1280 + 2 * i) * 256 + j, md) + ldf(W1, (size_t)(1536 + 2 * i) * 256 + j, md);
    v1 = ldf(W1, (size_t)(1281 + 2 * i) * 256 + j, md) + ldf(W1, (size_t)(1537 + 2 * i) * 256 + j, md);
    W5q[(((p >> 2) * 256 + j) << 2) + (p & 3)] = pack2(v0, v1);
    p = 384 + i;
    v0 = ldf(Wr, (size_t)(2 * i) * 256 + j, md);
    v1 = ldf(Wr, (size_t)(2 * i + 1) * 256 + j, md);
    W5q[(((p >> 2) * 256 + j) << 2) + (p & 3)] = pack2(v0, v1);
    p = 512 + i;
    v0 = ldf(Wh, (size_t)(2 * i) * 256 + j, md);
    v1 = ldf(Wh, (size_t)(2 * i + 1) * 256 + j, md);
    W5q[(((p >> 2) * 256 + j) << 2) + (p & 3)] = pack2(v0, v1);
  } else {
    int b = blockIdx.x - 128;  // 0..63
    float qv = ldf(q, (size_t)b * 256 + tid, md);
    qsh[tid] = qv;
    __syncthreads();
    float acc = ldf(b1, tid, md);
#pragma unroll 8
    for (int i = 0; i < 256; ++i) {
      float w = ldf(W1, (size_t)(256 + i) * 256 + tid, md) + ldf(W1, (size_t)(512 + i) * 256 + tid, md);
      acc = fmaf(qsh[i], w, acc);
    }
    qw1[b * 256 + tid] = acc;
    float ps = qv * ldf(Ws, tid, md);
    float pe = qv * ldf(We, tid, md);
    for (int o = 32; o > 0; o >>= 1) { ps += __shfl_down(ps, o); pe += __shfl_down(pe, o); }
    int wave = tid >> 6, lane = tid & 63;
    if (lane == 0) { reds[wave] = ps; rede[wave] = pe; }
    __syncthreads();
    if (tid == 0) {
      qs[b] = ldf(bs, 0, md) + reds[0] + reds[1] + reds[2] + reds[3];
      qe[b] = ldf(be, 0, md) + rede[0] + rede[1] + rede[2] + rede[3];
    }
  }
}

// ---------------- main GEMM via MFMA: att pre-softmax + xr/xh ----------------
// 64 t-rows per block (512 blocks, 512 threads, 8 waves): waves 0-3 own rows
// 0-31, waves 4-7 rows 32-63. xrh stores nontemporal. A-tile 97 KB LDS.
__launch_bounds__(512, 1)
__global__ void k_main(const void* __restrict__ fact,
                       const void* __restrict__ q,
                       const unsigned* __restrict__ W5q,
                       const float* __restrict__ qw1,
                       const void* __restrict__ W2,
                       const void* __restrict__ b2v,
                       const void* __restrict__ br,
                       const void* __restrict__ bh,
                       float* __restrict__ att,
                       unsigned* __restrict__ xrh) {
  __shared__ __align__(16) unsigned short A[64 * 776];  // 97 KB
  __shared__ float wsc[64][4];
  int md = detect_mode(fact);
  int blk = blockIdx.x;
  int b = blk >> 3, t0 = (blk & 7) * 64;
  int tid = threadIdx.x;  // 0..511
  {
    int c4 = (tid & 63) * 4;  // column group, fixed per thread
    int rg = tid >> 6;        // 0..7
    float4 q4 = ld4(q, (size_t)b * 256 + c4, md);
#pragma unroll
    for (int s = 0; s < 8; ++s) {
      int r = rg * 8 + s;  // 0..63
      float4 f4 = ld4(fact, ((size_t)(b * 512 + t0 + r)) * 256 + c4, md);
      char* base = (char*)A + (size_t)r * 1552 + (size_t)c4 * 2;
      uint2 w0 = {pack2(f4.x, f4.y), pack2(f4.z, f4.w)};
      uint2 w1 = {pack2(f4.x * q4.x, f4.y * q4.y), pack2(f4.z * q4.z, f4.w * q4.w)};
      uint2 w2 = {pack2(fabsf(f4.x - q4.x), fabsf(f4.y - q4.y)),
                  pack2(fabsf(f4.z - q4.z), fabsf(f4.w - q4.w))};
      *(uint2*)(base) = w0;
      *(uint2*)(base + 512) = w1;
      *(uint2*)(base + 1024) = w2;
    }
  }
  __syncthreads();
  int wv = tid >> 6, lane = tid & 63;
  int n16 = lane & 15, quad = lane >> 4;
  int rbase = (wv >> 2) * 32;        // 0 or 32
  int colb = (wv & 3) * 64 + n16;    // col-wave ownership
  const uint4* W4 = (const uint4*)W5q;
  f32x4 z = {0.f, 0.f, 0.f, 0.f};
  f32x4 u[2][4], ar[2][4], ah[2][4];
#pragma unroll
  for (int rt = 0; rt < 2; ++rt)
#pragma unroll
    for (int tile = 0; tile < 4; ++tile) { u[rt][tile] = z; ar[rt][tile] = z; ah[rt][tile] = z; }
#pragma unroll
  for (int kc = 0; kc < 8; ++kc) {
    uint4 av0 = *(const uint4*)((const char*)A + (rbase + n16) * 1552 + kc * 64 + quad * 16);
    uint4 av1 = *(const uint4*)((const char*)A + (rbase + 16 + n16) * 1552 + kc * 64 + quad * 16);
    bfrag af0 = __builtin_bit_cast(bfrag, av0);
    bfrag af1 = __builtin_bit_cast(bfrag, av1);
    int pg = kc * 4 + quad;
#pragma unroll
    for (int tile = 0; tile < 4; ++tile) {
      int col = colb + tile * 16;
      uint4 bu = W4[(size_t)pg * 256 + col];
      uint4 bw = W4[(size_t)(96 + pg) * 256 + col];
      uint4 bv = W4[(size_t)(128 + pg) * 256 + col];
      bfrag bfu = __builtin_bit_cast(bfrag, bu);
      bfrag bfw = __builtin_bit_cast(bfrag, bw);
      bfrag bfv = __builtin_bit_cast(bfrag, bv);
      u[0][tile] = __builtin_amdgcn_mfma_f32_16x16x32_bf16(af0, bfu, u[0][tile], 0, 0, 0);
      u[1][tile] = __builtin_amdgcn_mfma_f32_16x16x32_bf16(af1, bfu, u[1][tile], 0, 0, 0);
      ar[0][tile] = __builtin_amdgcn_mfma_f32_16x16x32_bf16(af0, bfw, ar[0][tile], 0, 0, 0);
      ar[1][tile] = __builtin_amdgcn_mfma_f32_16x16x32_bf16(af1, bfw, ar[1][tile], 0, 0, 0);
      ah[0][tile] = __builtin_amdgcn_mfma_f32_16x16x32_bf16(af0, bfv, ah[0][tile], 0, 0, 0);
      ah[1][tile] = __builtin_amdgcn_mfma_f32_16x16x32_bf16(af1, bfv, ah[1][tile], 0, 0, 0);
    }
  }
#pragma unroll
  for (int kc = 8; kc < 24; ++kc) {
    uint4 av0 = *(const uint4*)((const char*)A + (rbase + n16) * 1552 + kc * 64 + quad * 16);
    uint4 av1 = *(const uint4*)((const char*)A + (rbase + 16 + n16) * 1552 + kc * 64 + quad * 16);
    bfrag af0 = __builtin_bit_cast(bfrag, av0);
    bfrag af1 = __builtin_bit_cast(bfrag, av1);
    int pg = kc * 4 + quad;
#pragma unroll
    for (int tile = 0; tile < 4; ++tile) {
      int col = colb + tile * 16;
      uint4 bu = W4[(size_t)pg * 256 + col];
      bfrag bfu = __builtin_bit_cast(bfrag, bu);
      u[0][tile] = __builtin_amdgcn_mfma_f32_16x16x32_bf16(af0, bfu, u[0][tile], 0, 0, 0);
      u[1][tile] = __builtin_amdgcn_mfma_f32_16x16x32_bf16(af1, bfu, u[1][tile], 0, 0, 0);
    }
  }
  float qwv[4], w2v[4], brv[4], bhv[4];
#pragma unroll
  for (int tile = 0; tile < 4; ++tile) {
    int col = colb + tile * 16;
    qwv[tile] = qw1[b * 256 + col];
    w2v[tile] = ldf(W2, col, md);
    brv[tile] = ldf(br, col, md);
    bhv[tile] = ldf(bh, col, md);
  }
  float ps[2][4];
#pragma unroll
  for (int rt = 0; rt < 2; ++rt)
#pragma unroll
    for (int reg = 0; reg < 4; ++reg) {
      float p = 0.f;
#pragma unroll
      for (int tile = 0; tile < 4; ++tile) {
        float hid = fast_tanh(u[rt][tile][reg] + qwv[tile]);
        p = fmaf(hid, w2v[tile], p);
      }
      ps[rt][reg] = red16(p);
    }
  if (n16 == 0) {
#pragma unroll
    for (int rt = 0; rt < 2; ++rt)
#pragma unroll
      for (int reg = 0; reg < 4; ++reg)
        wsc[rbase + rt * 16 + quad * 4 + reg][wv & 3] = ps[rt][reg];
  }
  __syncthreads();
  if (tid < 64) {
    att[b * 512 + t0 + tid] =
        wsc[tid][0] + wsc[tid][1] + wsc[tid][2] + wsc[tid][3] + ldf(b2v, 0, md);
  }
#pragma unroll
  for (int rt = 0; rt < 2; ++rt)
#pragma unroll
    for (int tile = 0; tile < 4; ++tile) {
      int col = colb + tile * 16;
#pragma unroll
      for (int reg = 0; reg < 4; ++reg) {
        int t = t0 + rbase + rt * 16 + quad * 4 + reg;
        unsigned v = (unsigned)f2b(ar[rt][tile][reg] + brv[tile]) |
                     ((unsigned)f2b(ah[rt][tile][reg] + bhv[tile]) << 16);
        __builtin_nontemporal_store(v, &xrh[((size_t)(b * 512 + t)) * 256 + col]);
      }
    }
}

// ---------------- MFMA GRU scan: 4 batches/block, 16 blocks, 8 waves ----------------
// Round-3 structure + fused out-projection (deferred atomics) + fused softmax.
// gbuf/sacc/eacc padded to stride 520. Barriers are LDS-only (lgkmcnt drain,
// NOT vmcnt) so xrh/g prefetch loads stay in flight across the 16 barriers
// between issue and use.
__launch_bounds__(512, 2)
__global__ void k_scan(const unsigned* __restrict__ Urp,
                       const unsigned* __restrict__ Uhp,
                       const unsigned* __restrict__ xrh,
                       const float* __restrict__ att,
                       const int* __restrict__ input_len,
                       const void* __restrict__ Ws,
                       const void* __restrict__ We,
                       const float* __restrict__ qs,
                       const float* __restrict__ qe,
                       const void* __restrict__ fact,
                       float* __restrict__ out) {
  __shared__ __align__(16) unsigned short hB[4 * 272];
  __shared__ __align__(16) unsigned short rhB[4 * 272];
  __shared__ float sacc[4][520];
  __shared__ float eacc[4][520];
  __shared__ float gbuf[4][520];
  __shared__ float redx[8];
  int md = detect_mode(fact);
  int b0 = blockIdx.x * 4;
  int tid = threadIdx.x;  // 0..511
  int wv = tid >> 6, lane = tid & 63;
  int n16 = lane & 15, quad = lane >> 4;
  int col0 = wv * 32 + n16;
  int col1 = col0 + 16;
  uint4 br4[2][8], bh4[2][8];
#pragma unroll
  for (int tile = 0; tile < 2; ++tile) {
    int col = wv * 32 + tile * 16 + n16;
#pragma unroll
    for (int kc = 0; kc < 8; ++kc) {
      int p = kc * 16 + quad * 4;
      uint4 rv = {Urp[(size_t)p * 256 + col], Urp[(size_t)(p + 1) * 256 + col],
                  Urp[(size_t)(p + 2) * 256 + col], Urp[(size_t)(p + 3) * 256 + col]};
      uint4 hv = {Uhp[(size_t)p * 256 + col], Uhp[(size_t)(p + 1) * 256 + col],
                  Uhp[(size_t)(p + 2) * 256 + col], Uhp[(size_t)(p + 3) * 256 + col]};
      br4[tile][kc] = rv;
      bh4[tile][kc] = hv;
    }
  }
  for (int i = tid; i < 4 * 272; i += 512) { hB[i] = 0; rhB[i] = 0; }
  for (int i = tid; i < 2080; i += 512) { ((float*)sacc)[i] = 0.f; ((float*)eacc)[i] = 0.f; }
  // ---- fused softmax: att[b0+bb][:] -> gbuf[bb][:] ----
#pragma unroll
  for (int bb = 0; bb < 4; ++bb) {
    float v = att[(size_t)(b0 + bb) * 512 + tid];
    float m = v;
    for (int o = 32; o > 0; o >>= 1) m = fmaxf(m, __shfl_xor(m, o));
    if (lane == 0) redx[wv] = m;
    __syncthreads();
    m = redx[0];
#pragma unroll
    for (int w = 1; w < 8; ++w) m = fmaxf(m, redx[w]);
    float e = __expf(v - m);
    float s = e;
    for (int o = 32; o > 0; o >>= 1) s += __shfl_xor(s, o);
    __syncthreads();
    if (lane == 0) redx[wv] = s;
    __syncthreads();
    s = redx[0] + redx[1] + redx[2] + redx[3] + redx[4] + redx[5] + redx[6] + redx[7];
    gbuf[bb][tid] = e / s;
  }
  int mylen = input_len[b0 + quad];
  float ws0 = ldf(Ws, 256 + col0, md), ws1 = ldf(Ws, 256 + col1, md);
  float we0 = ldf(We, 256 + col0, md), we1 = ldf(We, 256 + col1, md);
  float hm0 = 0.f, hm1 = 0.f;  // this lane's h for (batch=quad, col0/col1)
  float pend_s = 0.f, pend_e = 0.f;
  int pend_T = 0;
  const char* hbase = (const char*)hB + (n16 >> 2) * 544 + quad * 16;
  const char* rhbase = (const char*)rhB + (n16 >> 2) * 544 + quad * 16;
  const unsigned* xrow = xrh + (size_t)(b0 + quad) * 512 * 256;

  unsigned xa[16], xbb[16];
  float4 ga0, ga1, gb0, gb1;
  __syncthreads();  // gbuf complete before prefetch reads it
  auto prefetch = [&](int tb, unsigned (&xr)[16], float4& g0, float4& g1) {
    const unsigned* xp = xrow + (size_t)tb * 8 * 256;
#pragma unroll
    for (int s = 0; s < 8; ++s) {
      xr[2 * s] = xp[s * 256 + col0];
      xr[2 * s + 1] = xp[s * 256 + col1];
    }
    g0 = *(const float4*)&gbuf[quad][tb * 8];
    g1 = *(const float4*)&gbuf[quad][tb * 8 + 4];
  };
  prefetch(0, xa, ga0, ga1);
  const f32x4 z4 = {0.f, 0.f, 0.f, 0.f};

  auto step = [&](int T, unsigned XC0, unsigned XC1, float GT) {
    // ---- phase A: rpre = h @ Ur (2 tiles, depth-2 chains) ----
    f32x4 accA[2][4];
#pragma unroll
    for (int tl = 0; tl < 2; ++tl)
#pragma unroll
      for (int j = 0; j < 4; ++j) accA[tl][j] = z4;
#pragma unroll
    for (int kc = 0; kc < 8; ++kc) {
      uint4 av = *(const uint4*)(hbase + kc * 64);
      bfrag af = __builtin_bit_cast(bfrag, av);
      int j = kc & 3;
      accA[0][j] = __builtin_amdgcn_mfma_f32_16x16x32_bf16(af, __builtin_bit_cast(bfrag, br4[0][kc]), accA[0][j], 0, 0, 0);
      accA[1][j] = __builtin_amdgcn_mfma_f32_16x16x32_bf16(af, __builtin_bit_cast(bfrag, br4[1][kc]), accA[1][j], 0, 0, 0);
    }
    // deferred out-projection reduce of PREVIOUS step — overlaps MFMA drain
    {
      float rs = red16(pend_s);
      float re_ = red16(pend_e);
      if (n16 == 0) {
        atomicAdd(&sacc[quad][pend_T], rs);
        atomicAdd(&eacc[quad][pend_T], re_);
      }
    }
    {
      float v0 = (accA[0][0][0] + accA[0][1][0]) + (accA[0][2][0] + accA[0][3][0]);
      float v1 = (accA[1][0][0] + accA[1][1][0]) + (accA[1][2][0] + accA[1][3][0]);
      float e0 = __expf(-(v0 + blo(XC0)));
      float e1 = __expf(-(v1 + blo(XC1)));
      float r0 = __builtin_amdgcn_rcpf(1.f + e0);
      float r1 = __builtin_amdgcn_rcpf(1.f + e1);
      rhB[quad * 272 + col0] = f2b(r0 * hm0);
      rhB[quad * 272 + col1] = f2b(r1 * hm1);
    }
    sync_lds();
    // ---- phase B: hpre = (r*h) @ Uh ----
    f32x4 accB[2][4];
#pragma unroll
    for (int tl = 0; tl < 2; ++tl)
#pragma unroll
      for (int j = 0; j < 4; ++j) accB[tl][j] = z4;
#pragma unroll
    for (int kc = 0; kc < 8; ++kc) {
      uint4 av = *(const uint4*)(rhbase + kc * 64);
      bfrag af = __builtin_bit_cast(bfrag, av);
      int j = kc & 3;
      accB[0][j] = __builtin_amdgcn_mfma_f32_16x16x32_bf16(af, __builtin_bit_cast(bfrag, bh4[0][kc]), accB[0][j], 0, 0, 0);
      accB[1][j] = __builtin_amdgcn_mfma_f32_16x16x32_bf16(af, __builtin_bit_cast(bfrag, bh4[1][kc]), accB[1][j], 0, 0, 0);
    }
    {
      float w0 = (accB[0][0][0] + accB[0][1][0]) + (accB[0][2][0] + accB[0][3][0]);
      float w1 = (accB[1][0][0] + accB[1][1][0]) + (accB[1][2][0] + accB[1][3][0]);
      float c0 = fminf(fmaxf(w0 + bhi(XC0), -15.f), 15.f);
      float c1 = fminf(fmaxf(w1 + bhi(XC1), -15.f), 15.f);
      float hc0 = 1.f - 2.f * __builtin_amdgcn_rcpf(__expf(2.f * c0) + 1.f);
      float hc1 = 1.f - 2.f * __builtin_amdgcn_rcpf(__expf(2.f * c1) + 1.f);
      bool valid = T < mylen;
      float hn0 = hm0 + GT * (hc0 - hm0);
      float hn1 = hm1 + GT * (hc1 - hm1);
      hm0 = valid ? hn0 : hm0;
      hm1 = valid ? hn1 : hm1;
      hB[quad * 272 + col0] = f2b(hm0);
      hB[quad * 272 + col1] = f2b(hm1);
      // stash out-projection partials; reduced during next phase A
      pend_s = valid ? fmaf(hm0, ws0, hm1 * ws1) : 0.f;
      pend_e = valid ? fmaf(hm0, we0, hm1 * we1) : 0.f;
      pend_T = T;
    }
    sync_lds();
  };

  for (int tb2 = 0; tb2 < 32; ++tb2) {
    prefetch(2 * tb2 + 1, xbb, gb0, gb1);
#pragma unroll
    for (int tt = 0; tt < 8; ++tt)
      step(tb2 * 16 + tt, xa[2 * tt], xa[2 * tt + 1], tt < 4 ? ga0[tt] : ga1[tt - 4]);
    prefetch(tb2 < 31 ? 2 * tb2 + 2 : 63, xa, ga0, ga1);
#pragma unroll
    for (int tt = 0; tt < 8; ++tt)
      step(tb2 * 16 + 8 + tt, xbb[2 * tt], xbb[2 * tt + 1], tt < 4 ? gb0[tt] : gb1[tt - 4]);
  }
  // final pending flush (T = 511)
  {
    float rs = red16(pend_s);
    float re_ = red16(pend_e);
    if (n16 == 0) {
      atomicAdd(&sacc[quad][pend_T], rs);
      atomicAdd(&eacc[quad][pend_T], re_);
    }
  }
  sync_lds();
  for (int i = tid; i < 2048; i += 512) {
    int b = i >> 9, t = i & 511;
    int row = (b0 + b) * 512 + t;
    out[row] = tanhf(qs[b0 + b] + sacc[b][t]);
    out[32768 + row] = tanhf(qe[b0 + b] + eacc[b][t]);
  }
}

extern "C" void kernel_launch(void* const* d_in, const int* in_sizes, int n_in,
                              void* d_out, int out_size, void* d_ws, size_t ws_size,
                              hipStream_t stream) {
  const void* q    = d_in[0];
  const void* fact = d_in[1];
  const int* ilen  = (const int*)d_in[2];
  const void* W1   = d_in[3];
  const void* b1   = d_in[4];
  const void* W2   = d_in[5];
  const void* b2v  = d_in[6];
  const void* Wr   = d_in[7];
  const void* Ur   = d_in[8];
  const void* br   = d_in[9];
  const void* Wh   = d_in[10];
  const void* Uh   = d_in[11];
  const void* bh   = d_in[12];
  const void* Ws   = d_in[13];
  const void* bs   = d_in[14];
  const void* We   = d_in[15];
  const void* be   = d_in[16];

  char* w = (char*)d_ws;
  unsigned* W5q = (unsigned*)(w);
  unsigned* Urp = (unsigned*)(w + 1310720);
  unsigned* Uhp = (unsigned*)(w + 1441792);
  float*    qw1 = (float*)(w + 1572864);
  float*    qs  = (float*)(w + 1638400);
  float*    qe  = (float*)(w + 1638656);
  float*    att = (float*)(w + 1638912);
  unsigned* xrh = (unsigned*)(w + 1901056);
  float* out = (float*)d_out;

  k_prep<<<dim3(192), dim3(256), 0, stream>>>(fact, W1, Wr, Wh, Ur, Uh, q, b1, Ws, bs, We, be,
                                              W5q, Urp, Uhp, qw1, qs, qe);
  k_main<<<dim3(512), dim3(512), 0, stream>>>(fact, q, W5q, qw1, W2, b2v, br, bh, att, xrh);
  k_scan<<<dim3(16), dim3(512), 0, stream>>>(Urp, Uhp, xrh, att, ilen, Ws, We, qs, qe, fact, out);
}